// Round 15
// baseline (2302.740 us; speedup 1.0000x reference)
//
#include <hip/hip_runtime.h>

typedef __attribute__((ext_vector_type(8))) short short8;
typedef __attribute__((ext_vector_type(4))) float f32x4;
typedef __attribute__((ext_vector_type(4))) unsigned u32x4;

__device__ __forceinline__ unsigned short f2bf(float f) {
  unsigned int u = __float_as_uint(f);
  u = (u + 0x7fffu + ((u >> 16) & 1u)) >> 16;
  return (unsigned short)u;
}

__device__ __forceinline__ void xp_store(float* p, float v) { *p = v; }
__device__ __forceinline__ void xp_store(unsigned short* p, float v) { *p = f2bf(v); }
__device__ __forceinline__ float xp_ld(const float* p) { return *p; }
__device__ __forceinline__ float xp_ld(const unsigned short* p) {
  return __uint_as_float(((unsigned int)*p) << 16);
}

// quad reduce via DPP (VALU pipe, no DS): sum over the 4 lanes of each quad.
__device__ __forceinline__ float quad_sum(float a) {
  float t1 = __int_as_float(
      __builtin_amdgcn_update_dpp(0, __float_as_int(a), 177, 0xf, 0xf, true));
  a += t1;
  float t2 = __int_as_float(
      __builtin_amdgcn_update_dpp(0, __float_as_int(a), 78, 0xf, 0xf, true));
  return a + t2;
}

// ---------------- prep: pack W_x and W_h (f32 -> bf16 pairs) ----------------
__global__ void prep_wx(const float* __restrict__ W, unsigned int* __restrict__ Wx2) {
  int i = blockIdx.x * 256 + threadIdx.x;  // 1024*128 dwords
  int g = i >> 7, kk = i & 127;
  float lo = W[(size_t)g * 512 + 256 + 2 * kk];
  float hi = W[(size_t)g * 512 + 256 + 2 * kk + 1];
  Wx2[i] = (unsigned int)f2bf(lo) | ((unsigned int)f2bf(hi) << 16);
}

__global__ void prep_wh(const float* __restrict__ W, unsigned int* __restrict__ Wh2) {
  int i = blockIdx.x * 256 + threadIdx.x;  // 1024*128 dwords
  int r = i >> 7, kk = i & 127;
  float lo = W[(size_t)r * 512 + 2 * kk];
  float hi = W[(size_t)r * 512 + 2 * kk + 1];
  Wh2[i] = (unsigned int)f2bf(lo) | ((unsigned int)f2bf(hi) << 16);
}

// ---------------- GEMM: xp[m][g] = sum_k x[m][k] * Wx[g][k] + b[g] ----------------
template <typename XPT>
__global__ __launch_bounds__(256, 4) void gemm_xp(const float* __restrict__ x,
                                                  const unsigned int* __restrict__ Wx2,
                                                  const float* __restrict__ bias,
                                                  XPT* __restrict__ xp) {
  __shared__ unsigned short As[128][40];
  __shared__ unsigned short Bs[128][40];
  const int m0 = blockIdx.y * 128, n0 = blockIdx.x * 128;
  const int tid = threadIdx.x, lane = tid & 63, w = tid >> 6;
  const int wr = w >> 1, wc = w & 1;
  const int r16 = lane & 15, kq = lane >> 4;
  f32x4 acc[4][4];
#pragma unroll
  for (int m = 0; m < 4; m++)
#pragma unroll
    for (int n = 0; n < 4; n++)
#pragma unroll
      for (int j = 0; j < 4; j++) acc[m][n][j] = 0.f;

  for (int kb = 0; kb < 256; kb += 32) {
    __syncthreads();
#pragma unroll
    for (int i = 0; i < 4; i++) {
      int idx = tid + i * 256;
      int row = idx >> 3, c4 = idx & 7;
      float4 v = *(const float4*)(x + (size_t)(m0 + row) * 256 + kb + c4 * 4);
      ushort4 s;
      s.x = f2bf(v.x); s.y = f2bf(v.y); s.z = f2bf(v.z); s.w = f2bf(v.w);
      *(ushort4*)&As[row][c4 * 4] = s;
    }
#pragma unroll
    for (int i = 0; i < 2; i++) {
      int idx = tid + i * 256;
      int row = idx >> 2, c = idx & 3;
      uint4 v = *(const uint4*)(Wx2 + (size_t)(n0 + row) * 128 + (kb >> 1) + c * 4);
      *(uint4*)&Bs[row][c * 8] = v;
    }
    __syncthreads();
    short8 a[4], bb[4];
#pragma unroll
    for (int m = 0; m < 4; m++)
      a[m] = *(const short8*)&As[wr * 64 + m * 16 + r16][kq * 8];
#pragma unroll
    for (int n = 0; n < 4; n++)
      bb[n] = *(const short8*)&Bs[wc * 64 + n * 16 + r16][kq * 8];
#pragma unroll
    for (int m = 0; m < 4; m++)
#pragma unroll
      for (int n = 0; n < 4; n++)
        acc[m][n] = __builtin_amdgcn_mfma_f32_16x16x32_bf16(a[m], bb[n], acc[m][n], 0, 0, 0);
  }
#pragma unroll
  for (int n = 0; n < 4; n++) {
    int gn = n0 + wc * 64 + n * 16 + r16;
    float bi = bias[gn];
#pragma unroll
    for (int m = 0; m < 4; m++) {
      int gm = m0 + wr * 64 + m * 16 + kq * 4;
#pragma unroll
      for (int j = 0; j < 4; j++) {
        xp_store(&xp[(size_t)(gm + j) * 1024 + gn], acc[m][n][j] + bi);
      }
    }
  }
}

// ---------------- recurrence: ONE BATCH PER CU, depth-2 chunk pipeline -------------
// 64 WGs x 1024 threads (16 waves/CU). Thread (u=tid>>2, p=tid&3): unit u's 4 gate
// rows over k-slice [p*64,p*64+64). Weights: 92 dwords resident (unified VGPR/AGPR,
// no scratch traffic per R13 FETCH); o-row + g-tail (36 dw/thread) stream from LDS.
// R12-R14 LESSON: removing DS insts (shuffles, xps, vmcnt drain) barely moved time
// -> the binding constraint is the SERIALIZED load->use chain: with the register
// file full, the compiler couldn't hoist chunk J+1's ds_read above chunk J's dots,
// exposing ~17 sequential LDS-queue latencies per step (~60% of the 5150cy step).
// R15: explicit depth-2 rotation over two (oj,hj) buffer pairs -- while chunk J is
// dotted from one pair, chunk J+2's reads are in flight into the other. The 2-buffer
// anti-dependencies bound transient pressure (+8 dw) so the allocator keeps the
// pipeline. Indexing identical to the R12-verified kernel; only load SCHEDULING
// changes. h: bf16 pairs, 2 slots x 4 p-copies stride 136 (conflict-free). p-reduce
// via DPP quad_perm. Raw barrier {lgkmcnt(0); s_barrier}. xp direct from global.
template <typename XPT>
__global__ __attribute__((amdgpu_flat_work_group_size(1024, 1024),
                          amdgpu_waves_per_eu(4, 4)))
void lstm_rec(const unsigned* __restrict__ Wh2,
              const XPT* __restrict__ xp,
              float* __restrict__ out) {
  __shared__ u32x4 wot[9 * 1024];          // 147456B: o-row (8) + g-tail (1), col-major
  __shared__ unsigned hsh[2][4][136];      // 4352B: h bf16-pairs, 2 slots x 4 p-copies

  const int tid = threadIdx.x;
  const int b = blockIdx.x;
  const int u = tid >> 2, p = tid & 3;
  const int brow0 = b << 10;

  // ---- weight register loads: f,i full rows + g pairs 0..27 (92 dwords)
  const unsigned* wf_p = Wh2 + (size_t)(0 * 256 + u) * 128 + (p << 5);
  const unsigned* wi_p = Wh2 + (size_t)(1 * 256 + u) * 128 + (p << 5);
  const unsigned* wg_p = Wh2 + (size_t)(2 * 256 + u) * 128 + (p << 5);
  const unsigned* wo_p = Wh2 + (size_t)(3 * 256 + u) * 128 + (p << 5);
  u32x4 wf0, wf1, wf2, wf3, wf4, wf5, wf6, wf7;
  u32x4 wi0, wi1, wi2, wi3, wi4, wi5, wi6, wi7;
  u32x4 wg0, wg1, wg2, wg3, wg4, wg5, wg6;
#define LOADROW8(P, R0, R1, R2, R3, R4, R5, R6, R7)                   \
  asm volatile("global_load_dwordx4 %0, %8, off\n\t"                  \
               "global_load_dwordx4 %1, %8, off offset:16\n\t"        \
               "global_load_dwordx4 %2, %8, off offset:32\n\t"        \
               "global_load_dwordx4 %3, %8, off offset:48\n\t"        \
               "global_load_dwordx4 %4, %8, off offset:64\n\t"        \
               "global_load_dwordx4 %5, %8, off offset:80\n\t"        \
               "global_load_dwordx4 %6, %8, off offset:96\n\t"        \
               "global_load_dwordx4 %7, %8, off offset:112"           \
               : "=&v"(R0), "=&v"(R1), "=&v"(R2), "=&v"(R3),          \
                 "=&v"(R4), "=&v"(R5), "=&v"(R6), "=&v"(R7)           \
               : "v"(P)                                               \
               : "memory")
#define LOADROW7(P, R0, R1, R2, R3, R4, R5, R6)                       \
  asm volatile("global_load_dwordx4 %0, %7, off\n\t"                  \
               "global_load_dwordx4 %1, %7, off offset:16\n\t"        \
               "global_load_dwordx4 %2, %7, off offset:32\n\t"        \
               "global_load_dwordx4 %3, %7, off offset:48\n\t"        \
               "global_load_dwordx4 %4, %7, off offset:64\n\t"        \
               "global_load_dwordx4 %5, %7, off offset:80\n\t"        \
               "global_load_dwordx4 %6, %7, off offset:96"            \
               : "=&v"(R0), "=&v"(R1), "=&v"(R2), "=&v"(R3),          \
                 "=&v"(R4), "=&v"(R5), "=&v"(R6)                      \
               : "v"(P)                                               \
               : "memory")
  LOADROW8(wf_p, wf0, wf1, wf2, wf3, wf4, wf5, wf6, wf7);
  LOADROW8(wi_p, wi0, wi1, wi2, wi3, wi4, wi5, wi6, wi7);
  LOADROW7(wg_p, wg0, wg1, wg2, wg3, wg4, wg5, wg6);
#undef LOADROW8
#undef LOADROW7
  asm volatile("s_waitcnt vmcnt(0)" ::: "memory");

  // ---- LDS weight staging: o-row chunks (E=0..7) + g tail (E=8), col-major
#pragma unroll
  for (int E = 0; E < 8; E++) wot[(E << 10) + tid] = *(const u32x4*)(wo_p + (E << 2));
  wot[(8 << 10) + tid] = *(const u32x4*)(wg_p + 28);

  // ---- zero both h slots
  for (int i = tid; i < 2 * 4 * 136; i += 1024) ((unsigned*)hsh)[i] = 0u;
  float c = 0.f;
  float* outp = out + ((size_t)brow0 << 8);
  __syncthreads();  // one full barrier before the loop (covers LDS init)

#define BAR() asm volatile("s_waitcnt lgkmcnt(0)\n\ts_barrier" ::: "memory")
#define DOT2(ACC, WD, HD) \
  asm("v_dot2_f32_bf16 %0, %1, %2, %0" : "+v"(ACC) : "v"(WD), "v"(HD))
// dot one chunk from pre-loaded registers (no LDS access here)
#define DOTC(WF, WI, WGQ, OJ, HJ)                                   \
  {                                                                 \
    DOT2(a0, WF[0], (HJ)[0]); DOT2(a0, WF[1], (HJ)[1]);             \
    DOT2(a0, WF[2], (HJ)[2]); DOT2(a0, WF[3], (HJ)[3]);             \
    DOT2(a1, WI[0], (HJ)[0]); DOT2(a1, WI[1], (HJ)[1]);             \
    DOT2(a1, WI[2], (HJ)[2]); DOT2(a1, WI[3], (HJ)[3]);             \
    DOT2(a2, (WGQ)[0], (HJ)[0]); DOT2(a2, (WGQ)[1], (HJ)[1]);       \
    DOT2(a2, (WGQ)[2], (HJ)[2]); DOT2(a2, (WGQ)[3], (HJ)[3]);       \
    DOT2(a3, (OJ)[0], (HJ)[0]); DOT2(a3, (OJ)[1], (HJ)[1]);         \
    DOT2(a3, (OJ)[2], (HJ)[2]); DOT2(a3, (OJ)[3], (HJ)[3]);         \
  }
#define HJC(HRX, J) (*(const u32x4*)&hsh[HRX][p][(p << 5) + ((J) << 2)])

#define STEP(T, HR, HW)                                                                \
  {                                                                                    \
    const int t = (T);                                                                 \
    /* xp for THIS step: direct global loads (VMEM pipe, consumed at gate add) */      \
    const XPT* xr = xp + ((size_t)(brow0 + t) << 10);                                  \
    float xv0 = xp_ld(xr + u);                                                         \
    float xv1 = xp_ld(xr + 256 + u);                                                   \
    float xv2 = xp_ld(xr + 512 + u);                                                   \
    float xv3 = xp_ld(xr + 768 + u);                                                   \
    /* depth-2 pipeline prologue: chunks 0,1 + g-tail in flight */                     \
    u32x4 gt7 = wot[(8 << 10) + tid];                                                  \
    u32x4 ojA = wot[(0 << 10) + tid];                                                  \
    u32x4 hjA = HJC(HR, 0);                                                            \
    u32x4 ojB = wot[(1 << 10) + tid];                                                  \
    u32x4 hjB = HJC(HR, 1);                                                            \
    float a0 = 0.f, a1 = 0.f, a2 = 0.f, a3 = 0.f;                                      \
    DOTC(wf0, wi0, wg0, ojA, hjA) ojA = wot[(2 << 10) + tid]; hjA = HJC(HR, 2);        \
    DOTC(wf1, wi1, wg1, ojB, hjB) ojB = wot[(3 << 10) + tid]; hjB = HJC(HR, 3);        \
    DOTC(wf2, wi2, wg2, ojA, hjA) ojA = wot[(4 << 10) + tid]; hjA = HJC(HR, 4);        \
    DOTC(wf3, wi3, wg3, ojB, hjB) ojB = wot[(5 << 10) + tid]; hjB = HJC(HR, 5);        \
    DOTC(wf4, wi4, wg4, ojA, hjA) ojA = wot[(6 << 10) + tid]; hjA = HJC(HR, 6);        \
    DOTC(wf5, wi5, wg5, ojB, hjB) ojB = wot[(7 << 10) + tid]; hjB = HJC(HR, 7);        \
    DOTC(wf6, wi6, wg6, ojA, hjA)                                                      \
    DOTC(wf7, wi7, gt7, ojB, hjB)                                                      \
    /* reduce over the 4 p-lanes: DPP quad_perm adds (VALU pipe, no DS) */             \
    a0 = quad_sum(a0); a1 = quad_sum(a1); a2 = quad_sum(a2); a3 = quad_sum(a3);        \
    float gf = a0 + xv0, gi = a1 + xv1, gg = a2 + xv2, go = a3 + xv3;                  \
    float f = 1.f / (1.f + __expf(-gf));                                               \
    float ii = 1.f / (1.f + __expf(-gi));                                              \
    float eg = __expf(2.f * gg);                                                       \
    float gtv = (eg - 1.f) / (eg + 1.f);                                               \
    float o = 1.f / (1.f + __expf(-go));                                               \
    c = f * c + ii * gtv;                                                              \
    float ec = __expf(2.f * c);                                                        \
    float tc = (ec - 1.f) / (ec + 1.f);                                                \
    float h = o * tc;                                                                  \
    /* publish: each lane writes its unit's bf16 into its own p-copy */                \
    ((unsigned short*)&hsh[HW][p][0])[u] = f2bf(h);                                    \
    if (p == 0) {                                                                      \
      __builtin_nontemporal_store(h, outp + ((size_t)t << 8) + u);                     \
      if (t == 1023) {                                                                 \
        out[16777216 + b * 256 + u] = h;                                               \
        out[16777216 + 16384 + b * 256 + u] = c;                                       \
      }                                                                                \
    }                                                                                  \
    /* raw barrier: LDS ordering only -- no vmcnt drain of out-store/xp loads */       \
    BAR();                                                                             \
  }

  for (int t2 = 0; t2 < 1024; t2 += 2) {
    STEP(t2, 1, 0)      // t even: read h slot1, write slot0
    STEP(t2 + 1, 0, 1)  // t odd:  read h slot0, write slot1
  }
#undef STEP
#undef HJC
#undef DOTC
#undef DOT2
#undef BAR
}

extern "C" void kernel_launch(void* const* d_in, const int* in_sizes, int n_in,
                              void* d_out, int out_size, void* d_ws, size_t ws_size,
                              hipStream_t stream) {
  (void)in_sizes; (void)n_in; (void)out_size;
  const float* x = (const float*)d_in[0];
  const float* W = (const float*)d_in[1];
  const float* bias = (const float*)d_in[2];
  float* out = (float*)d_out;
  char* ws = (char*)d_ws;

  unsigned int* Wx2 = (unsigned int*)ws;              // 524288 B
  unsigned int* Wh2 = (unsigned int*)(ws + 524288);   // 524288 B
  char* xpmem = ws + 1048576;

  const size_t need32 = 1048576 + (size_t)65536 * 1024 * 4;

  prep_wx<<<512, 256, 0, stream>>>(W, Wx2);
  prep_wh<<<512, 256, 0, stream>>>(W, Wh2);

  if (ws_size >= need32) {
    gemm_xp<float><<<dim3(8, 512), 256, 0, stream>>>(x, Wx2, bias, (float*)xpmem);
    lstm_rec<float><<<64, 1024, 0, stream>>>(Wh2, (const float*)xpmem, out);
  } else {
    gemm_xp<unsigned short><<<dim3(8, 512), 256, 0, stream>>>(x, Wx2, bias,
                                                              (unsigned short*)xpmem);
    lstm_rec<unsigned short><<<64, 1024, 0, stream>>>(Wh2, (const unsigned short*)xpmem, out);
  }
}

// Round 16
// 2103.882 us; speedup vs baseline: 1.0945x; 1.0945x over previous
//
#include <hip/hip_runtime.h>

typedef __attribute__((ext_vector_type(8))) short short8;
typedef __attribute__((ext_vector_type(4))) float f32x4;
typedef __attribute__((ext_vector_type(4))) unsigned u32x4;

__device__ __forceinline__ unsigned short f2bf(float f) {
  unsigned int u = __float_as_uint(f);
  u = (u + 0x7fffu + ((u >> 16) & 1u)) >> 16;
  return (unsigned short)u;
}

__device__ __forceinline__ void xp_store(float* p, float v) { *p = v; }
__device__ __forceinline__ void xp_store(unsigned short* p, float v) { *p = f2bf(v); }
__device__ __forceinline__ float xp_ld(const float* p) { return *p; }
__device__ __forceinline__ float xp_ld(const unsigned short* p) {
  return __uint_as_float(((unsigned int)*p) << 16);
}

// quad reduce via DPP (VALU pipe, no DS): sum over the 4 lanes of each quad.
__device__ __forceinline__ float quad_sum(float a) {
  float t1 = __int_as_float(
      __builtin_amdgcn_update_dpp(0, __float_as_int(a), 177, 0xf, 0xf, true));
  a += t1;
  float t2 = __int_as_float(
      __builtin_amdgcn_update_dpp(0, __float_as_int(a), 78, 0xf, 0xf, true));
  return a + t2;
}

// ---------------- prep: pack W_x and W_h (f32 -> bf16 pairs) ----------------
__global__ void prep_wx(const float* __restrict__ W, unsigned int* __restrict__ Wx2) {
  int i = blockIdx.x * 256 + threadIdx.x;  // 1024*128 dwords
  int g = i >> 7, kk = i & 127;
  float lo = W[(size_t)g * 512 + 256 + 2 * kk];
  float hi = W[(size_t)g * 512 + 256 + 2 * kk + 1];
  Wx2[i] = (unsigned int)f2bf(lo) | ((unsigned int)f2bf(hi) << 16);
}

__global__ void prep_wh(const float* __restrict__ W, unsigned int* __restrict__ Wh2) {
  int i = blockIdx.x * 256 + threadIdx.x;  // 1024*128 dwords
  int r = i >> 7, kk = i & 127;
  float lo = W[(size_t)r * 512 + 2 * kk];
  float hi = W[(size_t)r * 512 + 2 * kk + 1];
  Wh2[i] = (unsigned int)f2bf(lo) | ((unsigned int)f2bf(hi) << 16);
}

// ---------------- GEMM: xp[m][g] = sum_k x[m][k] * Wx[g][k] + b[g] ----------------
template <typename XPT>
__global__ __launch_bounds__(256, 4) void gemm_xp(const float* __restrict__ x,
                                                  const unsigned int* __restrict__ Wx2,
                                                  const float* __restrict__ bias,
                                                  XPT* __restrict__ xp) {
  __shared__ unsigned short As[128][40];
  __shared__ unsigned short Bs[128][40];
  const int m0 = blockIdx.y * 128, n0 = blockIdx.x * 128;
  const int tid = threadIdx.x, lane = tid & 63, w = tid >> 6;
  const int wr = w >> 1, wc = w & 1;
  const int r16 = lane & 15, kq = lane >> 4;
  f32x4 acc[4][4];
#pragma unroll
  for (int m = 0; m < 4; m++)
#pragma unroll
    for (int n = 0; n < 4; n++)
#pragma unroll
      for (int j = 0; j < 4; j++) acc[m][n][j] = 0.f;

  for (int kb = 0; kb < 256; kb += 32) {
    __syncthreads();
#pragma unroll
    for (int i = 0; i < 4; i++) {
      int idx = tid + i * 256;
      int row = idx >> 3, c4 = idx & 7;
      float4 v = *(const float4*)(x + (size_t)(m0 + row) * 256 + kb + c4 * 4);
      ushort4 s;
      s.x = f2bf(v.x); s.y = f2bf(v.y); s.z = f2bf(v.z); s.w = f2bf(v.w);
      *(ushort4*)&As[row][c4 * 4] = s;
    }
#pragma unroll
    for (int i = 0; i < 2; i++) {
      int idx = tid + i * 256;
      int row = idx >> 2, c = idx & 3;
      uint4 v = *(const uint4*)(Wx2 + (size_t)(n0 + row) * 128 + (kb >> 1) + c * 4);
      *(uint4*)&Bs[row][c * 8] = v;
    }
    __syncthreads();
    short8 a[4], bb[4];
#pragma unroll
    for (int m = 0; m < 4; m++)
      a[m] = *(const short8*)&As[wr * 64 + m * 16 + r16][kq * 8];
#pragma unroll
    for (int n = 0; n < 4; n++)
      bb[n] = *(const short8*)&Bs[wc * 64 + n * 16 + r16][kq * 8];
#pragma unroll
    for (int m = 0; m < 4; m++)
#pragma unroll
      for (int n = 0; n < 4; n++)
        acc[m][n] = __builtin_amdgcn_mfma_f32_16x16x32_bf16(a[m], bb[n], acc[m][n], 0, 0, 0);
  }
#pragma unroll
  for (int n = 0; n < 4; n++) {
    int gn = n0 + wc * 64 + n * 16 + r16;
    float bi = bias[gn];
#pragma unroll
    for (int m = 0; m < 4; m++) {
      int gm = m0 + wr * 64 + m * 16 + kq * 4;
#pragma unroll
      for (int j = 0; j < 4; j++) {
        xp_store(&xp[(size_t)(gm + j) * 1024 + gn], acc[m][n][j] + bi);
      }
    }
  }
}

// ---------------- recurrence: 512 threads x 256-VGPR budget, 2 units/thread --------
// 64 WGs x 512 threads (8 waves/CU, waves_per_eu(2,2) -> 256-reg budget).
// R8-R15 LESSON: at 1024 thr/128 regs, W_h bf16 (512KB) = the ENTIRE register file,
// forcing 28% LDS streaming + 16-wave lockstep; DS-count, conflicts, pipelining all
// null -> the 16-wave barrier chain was the floor. R16: thread (v=tid>>2, p=tid&3)
// owns TWO units (v, v+128) x 4 gates over k-slice [p*64,p*64+64). f,i,g rows of
// both units = 192 dw REGISTER-resident (48 named u32x4, asm-volatile loads); only
// the two o-rows (64 dw) stream from LDS wot[16][512] col-major (128KB). Barrier
// participants 16->8; same total VALU on half the waves (VALUBusy up, idle tail
// down). h: bf16 pairs, 2 slots x 4 p-copies stride 136 (verified conflict-free);
// DPP quad reduce; raw barrier {lgkmcnt(0); s_barrier}; xp direct from global.
template <typename XPT>
__global__ __attribute__((amdgpu_flat_work_group_size(512, 512),
                          amdgpu_waves_per_eu(2, 2)))
void lstm_rec(const unsigned* __restrict__ Wh2,
              const XPT* __restrict__ xp,
              float* __restrict__ out) {
  __shared__ u32x4 wot[16 * 512];          // 131072B: o-rows of units v / v+128
  __shared__ unsigned hsh[2][4][136];      // 4352B: h bf16-pairs, 2 slots x 4 p-copies

  const int tid = threadIdx.x;
  const int b = blockIdx.x;
  const int v = tid >> 2, p = tid & 3;
  const int brow0 = b << 10;

  // ---- weight register loads: f,i,g rows of units v and v+128 (192 dwords)
  const unsigned* fA_p = Wh2 + (size_t)(v) * 128 + (p << 5);
  const unsigned* iA_p = Wh2 + (size_t)(256 + v) * 128 + (p << 5);
  const unsigned* gA_p = Wh2 + (size_t)(512 + v) * 128 + (p << 5);
  const unsigned* oA_p = Wh2 + (size_t)(768 + v) * 128 + (p << 5);
  const unsigned* fB_p = Wh2 + (size_t)(128 + v) * 128 + (p << 5);
  const unsigned* iB_p = Wh2 + (size_t)(384 + v) * 128 + (p << 5);
  const unsigned* gB_p = Wh2 + (size_t)(640 + v) * 128 + (p << 5);
  const unsigned* oB_p = Wh2 + (size_t)(896 + v) * 128 + (p << 5);
  u32x4 fA0, fA1, fA2, fA3, fA4, fA5, fA6, fA7;
  u32x4 iA0, iA1, iA2, iA3, iA4, iA5, iA6, iA7;
  u32x4 gA0, gA1, gA2, gA3, gA4, gA5, gA6, gA7;
  u32x4 fB0, fB1, fB2, fB3, fB4, fB5, fB6, fB7;
  u32x4 iB0, iB1, iB2, iB3, iB4, iB5, iB6, iB7;
  u32x4 gB0, gB1, gB2, gB3, gB4, gB5, gB6, gB7;
#define LOADROW8(P, R0, R1, R2, R3, R4, R5, R6, R7)                   \
  asm volatile("global_load_dwordx4 %0, %8, off\n\t"                  \
               "global_load_dwordx4 %1, %8, off offset:16\n\t"        \
               "global_load_dwordx4 %2, %8, off offset:32\n\t"        \
               "global_load_dwordx4 %3, %8, off offset:48\n\t"        \
               "global_load_dwordx4 %4, %8, off offset:64\n\t"        \
               "global_load_dwordx4 %5, %8, off offset:80\n\t"        \
               "global_load_dwordx4 %6, %8, off offset:96\n\t"        \
               "global_load_dwordx4 %7, %8, off offset:112"           \
               : "=&v"(R0), "=&v"(R1), "=&v"(R2), "=&v"(R3),          \
                 "=&v"(R4), "=&v"(R5), "=&v"(R6), "=&v"(R7)           \
               : "v"(P)                                               \
               : "memory")
  LOADROW8(fA_p, fA0, fA1, fA2, fA3, fA4, fA5, fA6, fA7);
  LOADROW8(iA_p, iA0, iA1, iA2, iA3, iA4, iA5, iA6, iA7);
  LOADROW8(gA_p, gA0, gA1, gA2, gA3, gA4, gA5, gA6, gA7);
  LOADROW8(fB_p, fB0, fB1, fB2, fB3, fB4, fB5, fB6, fB7);
  LOADROW8(iB_p, iB0, iB1, iB2, iB3, iB4, iB5, iB6, iB7);
  LOADROW8(gB_p, gB0, gB1, gB2, gB3, gB4, gB5, gB6, gB7);
#undef LOADROW8
  asm volatile("s_waitcnt vmcnt(0)" ::: "memory");

  // ---- o-rows -> LDS col-major: chunks E=0..7 unit A, E=8..15 unit B
#pragma unroll
  for (int E = 0; E < 8; E++) {
    wot[(E << 9) + tid] = *(const u32x4*)(oA_p + (E << 2));
    wot[((E + 8) << 9) + tid] = *(const u32x4*)(oB_p + (E << 2));
  }

  // ---- zero both h slots
  for (int i = tid; i < 2 * 4 * 136; i += 512) ((unsigned*)hsh)[i] = 0u;
  float c0 = 0.f, c1 = 0.f;
  float* outp = out + ((size_t)brow0 << 8);
  __syncthreads();  // one full barrier before the loop (covers LDS init)

#define BAR() asm volatile("s_waitcnt lgkmcnt(0)\n\ts_barrier" ::: "memory")
#define DOT2(ACC, WD, HD) \
  asm("v_dot2_f32_bf16 %0, %1, %2, %0" : "+v"(ACC) : "v"(WD), "v"(HD))
// dot one chunk: 2 units x 4 gates x 4 dwords = 32 dot2, all register operands
#define DOTC(FA, IA, GA, FB, IB, GB, OA, OB, HJ)                    \
  {                                                                 \
    DOT2(aF0, FA[0], (HJ)[0]); DOT2(aF0, FA[1], (HJ)[1]);           \
    DOT2(aF0, FA[2], (HJ)[2]); DOT2(aF0, FA[3], (HJ)[3]);           \
    DOT2(aI0, IA[0], (HJ)[0]); DOT2(aI0, IA[1], (HJ)[1]);           \
    DOT2(aI0, IA[2], (HJ)[2]); DOT2(aI0, IA[3], (HJ)[3]);           \
    DOT2(aG0, GA[0], (HJ)[0]); DOT2(aG0, GA[1], (HJ)[1]);           \
    DOT2(aG0, GA[2], (HJ)[2]); DOT2(aG0, GA[3], (HJ)[3]);           \
    DOT2(aO0, (OA)[0], (HJ)[0]); DOT2(aO0, (OA)[1], (HJ)[1]);       \
    DOT2(aO0, (OA)[2], (HJ)[2]); DOT2(aO0, (OA)[3], (HJ)[3]);       \
    DOT2(aF1, FB[0], (HJ)[0]); DOT2(aF1, FB[1], (HJ)[1]);           \
    DOT2(aF1, FB[2], (HJ)[2]); DOT2(aF1, FB[3], (HJ)[3]);           \
    DOT2(aI1, IB[0], (HJ)[0]); DOT2(aI1, IB[1], (HJ)[1]);           \
    DOT2(aI1, IB[2], (HJ)[2]); DOT2(aI1, IB[3], (HJ)[3]);           \
    DOT2(aG1, GB[0], (HJ)[0]); DOT2(aG1, GB[1], (HJ)[1]);           \
    DOT2(aG1, GB[2], (HJ)[2]); DOT2(aG1, GB[3], (HJ)[3]);           \
    DOT2(aO1, (OB)[0], (HJ)[0]); DOT2(aO1, (OB)[1], (HJ)[1]);       \
    DOT2(aO1, (OB)[2], (HJ)[2]); DOT2(aO1, (OB)[3], (HJ)[3]);       \
  }
#define HJC(HRX, J) (*(const u32x4*)&hsh[HRX][p][(p << 5) + ((J) << 2)])

#define LSTM1(AF, AI, AG, AO, X0, X1, X2, X3, CC, HOUT)             \
  {                                                                 \
    float gf = AF + X0, gi = AI + X1, gg = AG + X2, go = AO + X3;   \
    float f = 1.f / (1.f + __expf(-gf));                            \
    float ii = 1.f / (1.f + __expf(-gi));                           \
    float eg = __expf(2.f * gg);                                    \
    float gtv = (eg - 1.f) / (eg + 1.f);                            \
    float o = 1.f / (1.f + __expf(-go));                            \
    CC = f * CC + ii * gtv;                                         \
    float ec = __expf(2.f * CC);                                    \
    float tc = (ec - 1.f) / (ec + 1.f);                             \
    HOUT = o * tc;                                                  \
  }

#define STEP(T, HR, HW)                                                                \
  {                                                                                    \
    const int t = (T);                                                                 \
    /* xp for THIS step: direct global loads (VMEM pipe, consumed at gate add) */      \
    const XPT* xr = xp + ((size_t)(brow0 + t) << 10);                                  \
    float xv0 = xp_ld(xr + v),        xv1 = xp_ld(xr + 256 + v);                       \
    float xv2 = xp_ld(xr + 512 + v),  xv3 = xp_ld(xr + 768 + v);                       \
    float xw0 = xp_ld(xr + 128 + v),  xw1 = xp_ld(xr + 384 + v);                       \
    float xw2 = xp_ld(xr + 640 + v),  xw3 = xp_ld(xr + 896 + v);                       \
    /* depth-2 pipeline over chunks */                                                 \
    u32x4 hX = HJC(HR, 0), oAX = wot[(0 << 9) + tid], oBX = wot[(8 << 9) + tid];       \
    u32x4 hY = HJC(HR, 1), oAY = wot[(1 << 9) + tid], oBY = wot[(9 << 9) + tid];       \
    float aF0 = 0.f, aI0 = 0.f, aG0 = 0.f, aO0 = 0.f;                                  \
    float aF1 = 0.f, aI1 = 0.f, aG1 = 0.f, aO1 = 0.f;                                  \
    DOTC(fA0, iA0, gA0, fB0, iB0, gB0, oAX, oBX, hX)                                   \
    hX = HJC(HR, 2); oAX = wot[(2 << 9) + tid]; oBX = wot[(10 << 9) + tid];            \
    DOTC(fA1, iA1, gA1, fB1, iB1, gB1, oAY, oBY, hY)                                   \
    hY = HJC(HR, 3); oAY = wot[(3 << 9) + tid]; oBY = wot[(11 << 9) + tid];            \
    DOTC(fA2, iA2, gA2, fB2, iB2, gB2, oAX, oBX, hX)                                   \
    hX = HJC(HR, 4); oAX = wot[(4 << 9) + tid]; oBX = wot[(12 << 9) + tid];            \
    DOTC(fA3, iA3, gA3, fB3, iB3, gB3, oAY, oBY, hY)                                   \
    hY = HJC(HR, 5); oAY = wot[(5 << 9) + tid]; oBY = wot[(13 << 9) + tid];            \
    DOTC(fA4, iA4, gA4, fB4, iB4, gB4, oAX, oBX, hX)                                   \
    hX = HJC(HR, 6); oAX = wot[(6 << 9) + tid]; oBX = wot[(14 << 9) + tid];            \
    DOTC(fA5, iA5, gA5, fB5, iB5, gB5, oAY, oBY, hY)                                   \
    hY = HJC(HR, 7); oAY = wot[(7 << 9) + tid]; oBY = wot[(15 << 9) + tid];            \
    DOTC(fA6, iA6, gA6, fB6, iB6, gB6, oAX, oBX, hX)                                   \
    DOTC(fA7, iA7, gA7, fB7, iB7, gB7, oAY, oBY, hY)                                   \
    /* reduce over the 4 p-lanes: DPP quad_perm adds (VALU pipe, no DS) */             \
    aF0 = quad_sum(aF0); aI0 = quad_sum(aI0); aG0 = quad_sum(aG0); aO0 = quad_sum(aO0);\
    aF1 = quad_sum(aF1); aI1 = quad_sum(aI1); aG1 = quad_sum(aG1); aO1 = quad_sum(aO1);\
    float h0v, h1v;                                                                    \
    LSTM1(aF0, aI0, aG0, aO0, xv0, xv1, xv2, xv3, c0, h0v)                             \
    LSTM1(aF1, aI1, aG1, aO1, xw0, xw1, xw2, xw3, c1, h1v)                             \
    /* publish: each lane writes both units' bf16 into its own p-copy */               \
    ((unsigned short*)&hsh[HW][p][0])[v] = f2bf(h0v);                                  \
    ((unsigned short*)&hsh[HW][p][0])[v + 128] = f2bf(h1v);                            \
    if (p == 0) {                                                                      \
      __builtin_nontemporal_store(h0v, outp + ((size_t)t << 8) + v);                   \
      __builtin_nontemporal_store(h1v, outp + ((size_t)t << 8) + v + 128);             \
      if (t == 1023) {                                                                 \
        out[16777216 + b * 256 + v] = h0v;                                             \
        out[16777216 + b * 256 + v + 128] = h1v;                                       \
        out[16777216 + 16384 + b * 256 + v] = c0;                                      \
        out[16777216 + 16384 + b * 256 + v + 128] = c1;                                \
      }                                                                                \
    }                                                                                  \
    /* raw barrier: LDS ordering only -- no vmcnt drain of out-store/xp loads */       \
    BAR();                                                                             \
  }

  for (int t2 = 0; t2 < 1024; t2 += 2) {
    STEP(t2, 1, 0)      // t even: read h slot1, write slot0
    STEP(t2 + 1, 0, 1)  // t odd:  read h slot0, write slot1
  }
#undef STEP
#undef LSTM1
#undef HJC
#undef DOTC
#undef DOT2
#undef BAR
}

extern "C" void kernel_launch(void* const* d_in, const int* in_sizes, int n_in,
                              void* d_out, int out_size, void* d_ws, size_t ws_size,
                              hipStream_t stream) {
  (void)in_sizes; (void)n_in; (void)out_size;
  const float* x = (const float*)d_in[0];
  const float* W = (const float*)d_in[1];
  const float* bias = (const float*)d_in[2];
  float* out = (float*)d_out;
  char* ws = (char*)d_ws;

  unsigned int* Wx2 = (unsigned int*)ws;              // 524288 B
  unsigned int* Wh2 = (unsigned int*)(ws + 524288);   // 524288 B
  char* xpmem = ws + 1048576;

  const size_t need32 = 1048576 + (size_t)65536 * 1024 * 4;

  prep_wx<<<512, 256, 0, stream>>>(W, Wx2);
  prep_wh<<<512, 256, 0, stream>>>(W, Wh2);

  if (ws_size >= need32) {
    gemm_xp<float><<<dim3(8, 512), 256, 0, stream>>>(x, Wx2, bias, (float*)xpmem);
    lstm_rec<float><<<64, 512, 0, stream>>>(Wh2, (const float*)xpmem, out);
  } else {
    gemm_xp<unsigned short><<<dim3(8, 512), 256, 0, stream>>>(x, Wx2, bias,
                                                              (unsigned short*)xpmem);
    lstm_rec<unsigned short><<<64, 512, 0, stream>>>(Wh2, (const unsigned short*)xpmem, out);
  }
}